// Round 12
// baseline (63.468 us; speedup 1.0000x reference)
//
#include <hip/hip_runtime.h>
#include <hip/hip_bf16.h>

// Problem constants
constexpr int B = 4, C = 64, H = 192, W = 192;
constexpr int HEADS = 4, D = 16;           // d = C/HEADS
constexpr int BLK = 8, HALO = 3, WIN = 14; // WIN = BLK + 2*HALO
constexpr int NH = H / BLK, NW = W / BLK;  // 24 x 24 windows
constexpr int HW = H * W;                  // 36864
constexpr int O = 3 * C;                   // 192 qkv channels

// attn LDS layout (units: shorts). K shrunk to 200 rows (tile-12 rows 200-207
// are masked junk keys; reads land in the V region, finite bf16). V planes
// pad-free. Total 52736 B -> allocates 53248 -> 3 blocks/CU with margin.
constexpr int K_ROWS = 200;
constexpr int K_OFF = 0;                   // K: [200 pixels][8 chunks x 8ch], XOR-swizzled
constexpr int V_OFF = K_ROWS * 64;         // 12800
constexpr int VPLANE = 208 * 16;           // V plane: [208 slots][16 ch]
constexpr int RH_OFF = V_OFF + 4 * VPLANE; // 26112: rel_h bf16 [16][8] (rows >=14 clamped)
constexpr int RW_OFF = RH_OFF + 128;       // rel_w bf16 [16][8]
constexpr int LDS_TOT = RW_OFF + 128;      // 26368 shorts = 52736 B

constexpr int K_ITEMS = K_ROWS * 8;        // 1600
constexpr int TOT_ITEMS = K_ITEMS + 208 * 8;  // 3264

typedef __attribute__((ext_vector_type(4))) short short4v;
typedef __attribute__((ext_vector_type(8))) short short8v;
typedef __attribute__((ext_vector_type(8))) __bf16 bf16x8;
typedef __attribute__((ext_vector_type(4))) float f32x4;

__device__ inline f32x4 mfma_bf16(short8v a, short8v b, f32x4 c) {
  return __builtin_amdgcn_mfma_f32_16x16x32_bf16(
      __builtin_bit_cast(bf16x8, a), __builtin_bit_cast(bf16x8, b), c, 0, 0, 0);
}

__device__ inline unsigned short f2bf(float f) {
  __bf16 h = (__bf16)f;
  return __builtin_bit_cast(unsigned short, h);
}

// packed bf16 pair: lo = bf16(a), hi = bf16(b) — single HW instr (T12)
__device__ inline unsigned cvt_pk_bf16(float a, float b) {
  unsigned r;
  asm("v_cvt_pk_bf16_f32 %0, %1, %2" : "=v"(r) : "v"(a), "v"(b));
  return r;
}

// ---------------------------------------------------------------------------
// Kernel 1: qkv projection as MFMA GEMM (unchanged; near HBM floor).
// q rows pre-scaled by d^-0.5 * log2(e) so attention works in exp2 domain.
// ---------------------------------------------------------------------------
__global__ __launch_bounds__(256) void qkv_mfma(
    const float* __restrict__ x, const float* __restrict__ w,
    unsigned short* __restrict__ qkv) {
  __shared__ unsigned short wlds[192 * 64];
  const int tid = threadIdx.x;

  const float4* wf4 = reinterpret_cast<const float4*>(w);
#pragma unroll
  for (int it = 0; it < 12; ++it) {
    const int idx = it * 256 + tid;  // 3072 float4s
    const int o = idx >> 4;
    const int c = (idx & 15) << 2;
    const float4 wv = wf4[idx];
    ushort4 st;
    st.x = f2bf(wv.x);
    st.y = f2bf(wv.y);
    st.z = f2bf(wv.z);
    st.w = f2bf(wv.w);
    const int sw = (((c >> 3) ^ (o & 7)) << 3) + (c & 4);
    *reinterpret_cast<ushort4*>(&wlds[o * 64 + sw]) = st;
  }

  const int wave = tid >> 6, lane = tid & 63;
  const int p = lane & 15, g = lane >> 4;
  const int pix_w = blockIdx.x * 128 + wave * 32;
  const int b = pix_w / HW;
  const int hw = pix_w - b * HW + p;
  const float* xb = x + (size_t)b * C * HW;

  short8v xf[2][2];
#pragma unroll
  for (int pt = 0; pt < 2; ++pt) {
#pragma unroll
    for (int ks = 0; ks < 2; ++ks) {
      unsigned short u[8];
#pragma unroll
      for (int j = 0; j < 8; ++j)
        u[j] = f2bf(xb[(size_t)(ks * 32 + g * 8 + j) * HW + hw + pt * 16]);
      unsigned int pw[4];
#pragma unroll
      for (int e = 0; e < 4; ++e)
        pw[e] = (unsigned int)u[2 * e] | ((unsigned int)u[2 * e + 1] << 16);
      xf[pt][ks] = __builtin_bit_cast(short8v, *reinterpret_cast<uint4*>(pw));
    }
  }
  __syncthreads();

#pragma unroll
  for (int ot = 0; ot < 12; ++ot) {
    short8v af[2];
#pragma unroll
    for (int ks = 0; ks < 2; ++ks)
      af[ks] = *reinterpret_cast<const short8v*>(
          wlds + (ot * 16 + p) * 64 + (((((ks << 2) | g)) ^ (p & 7)) << 3));
    // q pre-scale: d^-0.5 * log2(e) -> attention uses exp2 directly
    const float s = (ot < 4) ? 0.25f * 1.44269504f : 1.0f;
#pragma unroll
    for (int pt = 0; pt < 2; ++pt) {
      f32x4 acc = {0.f, 0.f, 0.f, 0.f};
      acc = mfma_bf16(af[0], xf[pt][0], acc);
      acc = mfma_bf16(af[1], xf[pt][1], acc);
      ushort4 st;
      st.x = f2bf(acc[0] * s);
      st.y = f2bf(acc[1] * s);
      st.z = f2bf(acc[2] * s);
      st.w = f2bf(acc[3] * s);
      *reinterpret_cast<ushort4*>(
          qkv + (size_t)(pix_w + pt * 16 + p) * O + ot * 16 + g * 4) = st;
    }
  }
}

// ---------------------------------------------------------------------------
// Kernel 2: MFMA window attention v9 = R10-passing structure verbatim, with
// ONLY the LDS footprint shrunk (K 200 rows + pad-free V) for 3 blocks/CU.
// Scalar softmax sum + shuffles retained (R11's sum-via-MFMA NaN'd; dropped).
// ---------------------------------------------------------------------------
__global__ __launch_bounds__(512, 4) void attn_kernel(
    const unsigned short* __restrict__ qkv,
    const float* __restrict__ rel_h, const float* __restrict__ rel_w,
    float* __restrict__ out) {
  __shared__ __align__(16) unsigned short lds[LDS_TOT];

  const int tid = threadIdx.x;
  const int blk = blockIdx.x;
  const int win = (blk & 7) * 288 + (blk >> 3);  // XCD swizzle (2304 % 8 == 0)
  const int b = win / (NH * NW);
  const int wrem = win - b * (NH * NW);
  const int bh = wrem / NW;
  const int bw = wrem - bh * NW;
  const int y0 = bh * BLK - HALO;
  const int x0 = bw * BLK - HALO;

  // ---- rel tables -> bf16 LDS (rows >= 14 clamped to 13) ----
  if (tid < 256) {
    const int i = tid & 127;
    const int rr = i >> 3, cc = i & 7;
    const int rc = (rr < WIN) ? rr : (WIN - 1);
    const float* src = (tid < 128) ? rel_h : rel_w;
    lds[((tid < 128) ? RH_OFF : RW_OFF) + i] = f2bf(src[rc * 8 + cc]);
  }

  // ---- staging phase 1: issue all K/V global loads (T14 split) ----
  // items 0..1599 = K (pixel 0..199, 8 chunks), 1600..3263 = V (208 x 8)
  uint4 raw[7];
#pragma unroll
  for (int it = 0; it < 7; ++it) {
    const int item = tid + it * 512;
    const bool isK = item < K_ITEMS;
    const int li = isK ? item : item - K_ITEMS;
    const int pixel = li >> 3;
    const int g = li & 7;
    const int wy = pixel / WIN;  // up to 14 for pad pixels
    const int wx = pixel - wy * WIN;
    const int y = y0 + wy, xx = x0 + wx;
    const bool inb = (item < TOT_ITEMS) & ((unsigned)y < (unsigned)H) &
                     ((unsigned)xx < (unsigned)W);
    uint4 rv = make_uint4(0u, 0u, 0u, 0u);
    if (inb)
      rv = *reinterpret_cast<const uint4*>(
          qkv + ((size_t)(b * HW + y * W + xx)) * O + (isK ? C : 2 * C) + g * 8);
    raw[it] = rv;
  }

  // ---- Q fragment prefetch (hq>=2 lanes supply q[0:8]/q[8:16] against the
  //      rel depth slots — no zero select anywhere) ----
  const int lane = tid & 63;
  const int wv = tid >> 6;
  const int head = wv & 3;
  const int qhalf = wv >> 2;
  const int r = lane & 15, hq = lane >> 4;
  const int qrow0 = qhalf * 32 + r;  // q2=0 row; q2=1 row = +16
  short8v qf0, qf1;
  {
    const int y = bh * BLK + (qrow0 >> 3);
    const int xx = bw * BLK + (qrow0 & 7);
    qf0 = *reinterpret_cast<const short8v*>(
        qkv + ((size_t)(b * HW + y * W + xx)) * O + head * D + (hq & 1) * 8);
    const int qrow1 = qrow0 + 16;
    const int y1 = bh * BLK + (qrow1 >> 3);
    const int xx1 = bw * BLK + (qrow1 & 7);
    qf1 = *reinterpret_cast<const short8v*>(
        qkv + ((size_t)(b * HW + y1 * W + xx1)) * O + head * D + (hq & 1) * 8);
  }

  // ---- staging phase 2: LDS writes (pure copies) ----
#pragma unroll
  for (int it = 0; it < 7; ++it) {
    const int item = tid + it * 512;
    if (item < TOT_ITEMS) {
      const bool isK = item < K_ITEMS;
      const int li = isK ? item : item - K_ITEMS;
      const int pixel = li >> 3;
      const int g = li & 7;
      if (isK) {
        const int ch = (g ^ pixel) & 7;  // chunk XOR swizzle
        *reinterpret_cast<uint4*>(&lds[K_OFF + pixel * 64 + ch * 8]) = raw[it];
      } else {
        const int hd = g >> 1, c8 = g & 1;
        *reinterpret_cast<uint4*>(
            &lds[V_OFF + hd * VPLANE + pixel * 16 + c8 * 8]) = raw[it];
      }
    }
  }
  __syncthreads();

  // ---- per-lane A-frag LDS offsets (shorts), one per QK tile ----
  // hq<2: K row chunks; hq==2: rel_h[wy]; hq==3: rel_w[wx].
  // Tile 12 rows 200-207 read V-region junk (finite); those keys' p = 0.
  int koff[13];
#pragma unroll
  for (int t = 0; t < 13; ++t) {
    const int row = 16 * t + r;
    const int wy = row / WIN;
    const int wx = row - wy * WIN;
    const int a_k =
        K_OFF + row * 64 + ((((head << 1) | (hq & 1)) ^ (row & 7)) << 3);
    const int a_rh = RH_OFF + wy * 8;
    const int a_rw = RW_OFF + wx * 8;
    koff[t] = (hq < 2) ? a_k : ((hq == 2) ? a_rh : a_rw);
  }

  // ---- V^T fragments via hardware transpose-read (per-lane addr):
  //      lane l supplies base + 8*l; lane(r,hq) elem j = V[32*tau+4*hq+j][r];
  //      offset:512 gives +16 slots. ----
  const unsigned vbase_addr =
      (unsigned)(unsigned long long)(const void*)&lds[V_OFF + head * VPLANE] +
      (unsigned)(lane * 8);
  short4v vlo[7], vhi[7];
#pragma unroll
  for (int tau = 0; tau < 7; ++tau) {
    const unsigned va = vbase_addr + tau * 1024;
    asm volatile("ds_read_b64_tr_b16 %0, %1" : "=v"(vlo[tau]) : "v"(va));
    if (tau < 6) {
      asm volatile("ds_read_b64_tr_b16 %0, %1 offset:512"
                   : "=v"(vhi[tau])
                   : "v"(va));
    } else {
      vhi[tau] = (short4v){0, 0, 0, 0};  // slots 208-223: pf is 0 anyway
    }
  }
  asm volatile("s_waitcnt lgkmcnt(0)" ::: "memory");
  __builtin_amdgcn_sched_barrier(0);

  __builtin_amdgcn_s_setprio(1);

  // ---- fused streaming pass: QK -> exp2 -> pack -> PV, both q2 at once ----
  f32x4 oacc0 = {0.f, 0.f, 0.f, 0.f}, oacc1 = {0.f, 0.f, 0.f, 0.f};
  float sum0 = 0.f, sum1 = 0.f;
#pragma unroll
  for (int tau = 0; tau < 7; ++tau) {
    unsigned pw0[4], pw1[4];
#pragma unroll
    for (int half = 0; half < 2; ++half) {
      const int t = 2 * tau + half;
      if (t < 13) {
        const short8v kf = *reinterpret_cast<const short8v*>(&lds[koff[t]]);
        const f32x4 z4 = {0.f, 0.f, 0.f, 0.f};
        const f32x4 s0 = mfma_bf16(kf, qf0, z4);
        const f32x4 s1 = mfma_bf16(kf, qf1, z4);
        float p0e[4], p1e[4];
#pragma unroll
        for (int e = 0; e < 4; ++e) {
          float pa = __builtin_amdgcn_exp2f(s0[e]);
          float pb = __builtin_amdgcn_exp2f(s1[e]);
          if (t == 12 && hq >= 1) {  // keys >= 196: pad
            pa = 0.f;
            pb = 0.f;
          }
          sum0 += pa;
          sum1 += pb;
          p0e[e] = pa;
          p1e[e] = pb;
        }
        pw0[half * 2 + 0] = cvt_pk_bf16(p0e[0], p0e[1]);
        pw0[half * 2 + 1] = cvt_pk_bf16(p0e[2], p0e[3]);
        pw1[half * 2 + 0] = cvt_pk_bf16(p1e[0], p1e[1]);
        pw1[half * 2 + 1] = cvt_pk_bf16(p1e[2], p1e[3]);
      } else {  // tau == 6 high half: keys 208-223 virtual
        pw0[2] = 0u;
        pw0[3] = 0u;
        pw1[2] = 0u;
        pw1[3] = 0u;
      }
    }
    const short8v vf =
        __builtin_shufflevector(vlo[tau], vhi[tau], 0, 1, 2, 3, 4, 5, 6, 7);
    const uint4 u0 = make_uint4(pw0[0], pw0[1], pw0[2], pw0[3]);
    const uint4 u1 = make_uint4(pw1[0], pw1[1], pw1[2], pw1[3]);
    oacc0 = mfma_bf16(vf, __builtin_bit_cast(short8v, u0), oacc0);
    oacc1 = mfma_bf16(vf, __builtin_bit_cast(short8v, u1), oacc1);
  }

  // ---- softmax denominators (row spread across lane groups ^16, ^32) ----
  sum0 += __shfl_xor(sum0, 16);
  sum0 += __shfl_xor(sum0, 32);
  sum1 += __shfl_xor(sum1, 16);
  sum1 += __shfl_xor(sum1, 32);
  const float inv0 = 1.f / sum0;
  const float inv1 = 1.f / sum1;

  // ---- epilogue: lane holds O^T[c=4*hq+e][qrow]; scale by 1/sum ----
  {
    const int y = bh * BLK + (qrow0 >> 3);
    const int xx = bw * BLK + (qrow0 & 7);
    float* op = out + ((size_t)b * C + head * D + 4 * hq) * HW + y * W + xx;
#pragma unroll
    for (int e = 0; e < 4; ++e) op[(size_t)e * HW] = oacc0[e] * inv0;
  }
  {
    const int qrow1 = qrow0 + 16;
    const int y = bh * BLK + (qrow1 >> 3);
    const int xx = bw * BLK + (qrow1 & 7);
    float* op = out + ((size_t)b * C + head * D + 4 * hq) * HW + y * W + xx;
#pragma unroll
    for (int e = 0; e < 4; ++e) op[(size_t)e * HW] = oacc1[e] * inv1;
  }
  __builtin_amdgcn_s_setprio(0);
}

extern "C" void kernel_launch(void* const* d_in, const int* in_sizes, int n_in,
                              void* d_out, int out_size, void* d_ws,
                              size_t ws_size, hipStream_t stream) {
  const float* x = (const float*)d_in[0];      // (4, 64, 192, 192)
  const float* w_qkv = (const float*)d_in[1];  // (192, 64)
  const float* rel_h = (const float*)d_in[2];  // (1, 14, 1, 8)
  const float* rel_w = (const float*)d_in[3];  // (1, 1, 14, 8)
  float* out = (float*)d_out;                  // (4, 64, 192, 192)

  unsigned short* qkv = (unsigned short*)d_ws;  // (B, H, W, O) bf16

  qkv_mfma<<<B * HW / 128, 256, 0, stream>>>(x, w_qkv, qkv);
  attn_kernel<<<B * NH * NW, 512, 0, stream>>>(qkv, rel_h, rel_w, out);
}

// Round 14
// 62.811 us; speedup vs baseline: 1.0105x; 1.0105x over previous
//
#include <hip/hip_runtime.h>
#include <hip/hip_bf16.h>

// Problem constants
constexpr int B = 4, C = 64, H = 192, W = 192;
constexpr int HEADS = 4, D = 16;           // d = C/HEADS
constexpr int BLK = 8, HALO = 3, WIN = 14; // WIN = BLK + 2*HALO
constexpr int NH = H / BLK, NW = W / BLK;  // 24 x 24 windows
constexpr int HW = H * W;                  // 36864
constexpr int O = 3 * C;                   // 192 qkv channels

// attn LDS layout (units: shorts). One block = one window x 2 heads.
// K: [200 rows][stride 32] = 2 heads x 2 chunks x 8ch, 4-chunk XOR swizzle.
// K padded to 6656 so V plane 0 starts 1024-B aligned (13312 B) — every
// passing kernel had plane-0 1024-aligned; R13 (failed) did not.
// V: 2 planes of [208][16], stride 3344 shorts (R10-proven plane stride).
constexpr int K_ROWS = 200;
constexpr int KSTRIDE = 32;                 // shorts per K row (64 B)
constexpr int K_OFF = 0;
constexpr int V_OFF = 6656;                 // 13312 B, 1024-aligned
constexpr int VPLANE = 208 * 16 + 16;       // 3344 shorts per head plane
constexpr int RH_OFF = V_OFF + 2 * VPLANE;  // 13344: rel_h bf16 [16][8]
constexpr int RW_OFF = RH_OFF + 128;        // rel_w bf16 [16][8]
constexpr int LDS_TOT = RW_OFF + 128;       // 13600 shorts = 27200 B

constexpr int K_ITEMS = K_ROWS * 4;         // 800 (pixel x {2 heads x 2 chunks})
constexpr int TOT_ITEMS = K_ITEMS + 208 * 4;  // 1632

typedef __attribute__((ext_vector_type(4))) short short4v;
typedef __attribute__((ext_vector_type(8))) short short8v;
typedef __attribute__((ext_vector_type(8))) __bf16 bf16x8;
typedef __attribute__((ext_vector_type(4))) float f32x4;

__device__ inline f32x4 mfma_bf16(short8v a, short8v b, f32x4 c) {
  return __builtin_amdgcn_mfma_f32_16x16x32_bf16(
      __builtin_bit_cast(bf16x8, a), __builtin_bit_cast(bf16x8, b), c, 0, 0, 0);
}

__device__ inline unsigned short f2bf(float f) {
  __bf16 h = (__bf16)f;
  return __builtin_bit_cast(unsigned short, h);
}

// packed bf16 pair: lo = bf16(a), hi = bf16(b) — single HW instr (T12)
__device__ inline unsigned cvt_pk_bf16(float a, float b) {
  unsigned r;
  asm("v_cvt_pk_bf16_f32 %0, %1, %2" : "=v"(r) : "v"(a), "v"(b));
  return r;
}

// ---------------------------------------------------------------------------
// Kernel 1: qkv projection as MFMA GEMM (unchanged; near HBM floor).
// q rows pre-scaled by d^-0.5 * log2(e) so attention works in exp2 domain.
// ---------------------------------------------------------------------------
__global__ __launch_bounds__(256) void qkv_mfma(
    const float* __restrict__ x, const float* __restrict__ w,
    unsigned short* __restrict__ qkv) {
  __shared__ unsigned short wlds[192 * 64];
  const int tid = threadIdx.x;

  const float4* wf4 = reinterpret_cast<const float4*>(w);
#pragma unroll
  for (int it = 0; it < 12; ++it) {
    const int idx = it * 256 + tid;  // 3072 float4s
    const int o = idx >> 4;
    const int c = (idx & 15) << 2;
    const float4 wv = wf4[idx];
    ushort4 st;
    st.x = f2bf(wv.x);
    st.y = f2bf(wv.y);
    st.z = f2bf(wv.z);
    st.w = f2bf(wv.w);
    const int sw = (((c >> 3) ^ (o & 7)) << 3) + (c & 4);
    *reinterpret_cast<ushort4*>(&wlds[o * 64 + sw]) = st;
  }

  const int wave = tid >> 6, lane = tid & 63;
  const int p = lane & 15, g = lane >> 4;
  const int pix_w = blockIdx.x * 128 + wave * 32;
  const int b = pix_w / HW;
  const int hw = pix_w - b * HW + p;
  const float* xb = x + (size_t)b * C * HW;

  short8v xf[2][2];
#pragma unroll
  for (int pt = 0; pt < 2; ++pt) {
#pragma unroll
    for (int ks = 0; ks < 2; ++ks) {
      unsigned short u[8];
#pragma unroll
      for (int j = 0; j < 8; ++j)
        u[j] = f2bf(xb[(size_t)(ks * 32 + g * 8 + j) * HW + hw + pt * 16]);
      unsigned int pw[4];
#pragma unroll
      for (int e = 0; e < 4; ++e)
        pw[e] = (unsigned int)u[2 * e] | ((unsigned int)u[2 * e + 1] << 16);
      xf[pt][ks] = __builtin_bit_cast(short8v, *reinterpret_cast<uint4*>(pw));
    }
  }
  __syncthreads();

#pragma unroll
  for (int ot = 0; ot < 12; ++ot) {
    short8v af[2];
#pragma unroll
    for (int ks = 0; ks < 2; ++ks)
      af[ks] = *reinterpret_cast<const short8v*>(
          wlds + (ot * 16 + p) * 64 + (((((ks << 2) | g)) ^ (p & 7)) << 3));
    // q pre-scale: d^-0.5 * log2(e) -> attention uses exp2 directly
    const float s = (ot < 4) ? 0.25f * 1.44269504f : 1.0f;
#pragma unroll
    for (int pt = 0; pt < 2; ++pt) {
      f32x4 acc = {0.f, 0.f, 0.f, 0.f};
      acc = mfma_bf16(af[0], xf[pt][0], acc);
      acc = mfma_bf16(af[1], xf[pt][1], acc);
      ushort4 st;
      st.x = f2bf(acc[0] * s);
      st.y = f2bf(acc[1] * s);
      st.z = f2bf(acc[2] * s);
      st.w = f2bf(acc[3] * s);
      *reinterpret_cast<ushort4*>(
          qkv + (size_t)(pix_w + pt * 16 + p) * O + ot * 16 + g * 4) = st;
    }
  }
}

// ---------------------------------------------------------------------------
// Kernel 2: MFMA window attention v11 = R12-proven per-wave core, re-tiled to
// one block = (window, head-pair): 256 thr = 4 waves, LDS 27.2 KB ->
// 5 blocks/CU cap. K 4-chunk XOR (involution on both sides); V plane 0
// 1024-B aligned (the one geometry property all passing kernels shared).
// ---------------------------------------------------------------------------
__global__ __launch_bounds__(256, 4) void attn_kernel(
    const unsigned short* __restrict__ qkv,
    const float* __restrict__ rel_h, const float* __restrict__ rel_w,
    float* __restrict__ out) {
  __shared__ __align__(16) unsigned short lds[LDS_TOT];

  const int tid = threadIdx.x;
  const int blk = blockIdx.x;
  const int hpair = blk & 1;            // heads {0,1} or {2,3}
  const int wr = blk >> 1;              // window index pre-swizzle
  const int win = (wr & 7) * 288 + (wr >> 3);  // XCD swizzle (2304 % 8 == 0)
  const int b = win / (NH * NW);
  const int wrem = win - b * (NH * NW);
  const int bh = wrem / NW;
  const int bw = wrem - bh * NW;
  const int y0 = bh * BLK - HALO;
  const int x0 = bw * BLK - HALO;

  // ---- rel tables -> bf16 LDS (rows >= 14 clamped to 13) ----
  {
    const int i = tid & 127;
    const int rr = i >> 3, cc = i & 7;
    const int rc = (rr < WIN) ? rr : (WIN - 1);
    const float* src = (tid < 128) ? rel_h : rel_w;
    lds[((tid < 128) ? RH_OFF : RW_OFF) + i] = f2bf(src[rc * 8 + cc]);
  }

  // ---- staging phase 1: issue all K/V global loads (T14 split) ----
  // items 0..799 = K (200 pixels x 4 chunks), 800..1631 = V (208 x 4)
  uint4 raw[7];
#pragma unroll
  for (int it = 0; it < 7; ++it) {
    const int item = tid + it * 256;
    const bool isK = item < K_ITEMS;
    const int li = isK ? item : item - K_ITEMS;
    const int pixel = li >> 2;
    const int g = li & 3;  // (local head << 1) | chunk
    const int wy = pixel / WIN;
    const int wx = pixel - wy * WIN;
    const int y = y0 + wy, xx = x0 + wx;
    const bool inb = (item < TOT_ITEMS) & ((unsigned)y < (unsigned)H) &
                     ((unsigned)xx < (unsigned)W);
    uint4 rv = make_uint4(0u, 0u, 0u, 0u);
    if (inb)
      rv = *reinterpret_cast<const uint4*>(
          qkv + ((size_t)(b * HW + y * W + xx)) * O + (isK ? C : 2 * C) +
          (hpair << 5) + (g << 3));
    raw[it] = rv;
  }

  // ---- Q fragment prefetch (hq>=2 lanes supply q[0:8]/q[8:16] against the
  //      rel depth slots — no zero select anywhere) ----
  const int lane = tid & 63;
  const int wv = tid >> 6;              // 0..3
  const int lh = wv & 1;                // local head
  const int head = hpair * 2 + lh;      // global head
  const int qhalf = wv >> 1;
  const int r = lane & 15, hq = lane >> 4;
  const int qrow0 = qhalf * 32 + r;     // q2=0 row; q2=1 row = +16
  short8v qf0, qf1;
  {
    const int y = bh * BLK + (qrow0 >> 3);
    const int xx = bw * BLK + (qrow0 & 7);
    qf0 = *reinterpret_cast<const short8v*>(
        qkv + ((size_t)(b * HW + y * W + xx)) * O + head * D + (hq & 1) * 8);
    const int qrow1 = qrow0 + 16;
    const int y1 = bh * BLK + (qrow1 >> 3);
    const int xx1 = bw * BLK + (qrow1 & 7);
    qf1 = *reinterpret_cast<const short8v*>(
        qkv + ((size_t)(b * HW + y1 * W + xx1)) * O + head * D + (hq & 1) * 8);
  }

  // ---- staging phase 2: LDS writes ----
#pragma unroll
  for (int it = 0; it < 7; ++it) {
    const int item = tid + it * 256;
    if (item < TOT_ITEMS) {
      const bool isK = item < K_ITEMS;
      const int li = isK ? item : item - K_ITEMS;
      const int pixel = li >> 2;
      const int g = li & 3;
      if (isK) {
        const int ch = (g ^ pixel) & 3;  // 4-chunk XOR swizzle
        *reinterpret_cast<uint4*>(&lds[K_OFF + pixel * KSTRIDE + ch * 8]) =
            raw[it];
      } else {
        const int vlh = g >> 1, c8 = g & 1;
        *reinterpret_cast<uint4*>(
            &lds[V_OFF + vlh * VPLANE + pixel * 16 + c8 * 8]) = raw[it];
      }
    }
  }
  __syncthreads();

  // ---- per-lane A-frag LDS offsets (shorts), one per QK tile ----
  // hq<2: K row chunks (XOR'd); hq==2: rel_h[wy]; hq==3: rel_w[wx].
  // Tile 12 rows 200-207 read K-pad junk (finite LDS); those keys' p = 0.
  int koff[13];
#pragma unroll
  for (int t = 0; t < 13; ++t) {
    const int row = 16 * t + r;
    const int wy = row / WIN;
    const int wx = row - wy * WIN;
    const int a_k =
        K_OFF + row * KSTRIDE + (((((lh << 1) | (hq & 1)) ^ row) & 3) << 3);
    const int a_rh = RH_OFF + wy * 8;
    const int a_rw = RW_OFF + wx * 8;
    koff[t] = (hq < 2) ? a_k : ((hq == 2) ? a_rh : a_rw);
  }

  // ---- V^T fragments via hardware transpose-read (per-lane addr):
  //      lane l supplies base + 8*l; lane(r,hq) elem j = V[32*tau+4*hq+j][r];
  //      offset:512 gives +16 slots. ----
  const unsigned vbase_addr =
      (unsigned)(unsigned long long)(const void*)&lds[V_OFF + lh * VPLANE] +
      (unsigned)(lane * 8);
  short4v vlo[7], vhi[7];
#pragma unroll
  for (int tau = 0; tau < 7; ++tau) {
    const unsigned va = vbase_addr + tau * 1024;
    asm volatile("ds_read_b64_tr_b16 %0, %1" : "=v"(vlo[tau]) : "v"(va));
    if (tau < 6) {
      asm volatile("ds_read_b64_tr_b16 %0, %1 offset:512"
                   : "=v"(vhi[tau])
                   : "v"(va));
    } else {
      vhi[tau] = (short4v){0, 0, 0, 0};  // slots 208-223: pf is 0 anyway
    }
  }
  asm volatile("s_waitcnt lgkmcnt(0)" ::: "memory");
  __builtin_amdgcn_sched_barrier(0);

  __builtin_amdgcn_s_setprio(1);

  // ---- fused streaming pass: QK -> exp2 -> pack -> PV, both q2 at once ----
  f32x4 oacc0 = {0.f, 0.f, 0.f, 0.f}, oacc1 = {0.f, 0.f, 0.f, 0.f};
  float sum0 = 0.f, sum1 = 0.f;
#pragma unroll
  for (int tau = 0; tau < 7; ++tau) {
    unsigned pw0[4], pw1[4];
#pragma unroll
    for (int half = 0; half < 2; ++half) {
      const int t = 2 * tau + half;
      if (t < 13) {
        const short8v kf = *reinterpret_cast<const short8v*>(&lds[koff[t]]);
        const f32x4 z4 = {0.f, 0.f, 0.f, 0.f};
        const f32x4 s0 = mfma_bf16(kf, qf0, z4);
        const f32x4 s1 = mfma_bf16(kf, qf1, z4);
        float p0e[4], p1e[4];
#pragma unroll
        for (int e = 0; e < 4; ++e) {
          float pa = __builtin_amdgcn_exp2f(s0[e]);
          float pb = __builtin_amdgcn_exp2f(s1[e]);
          if (t == 12 && hq >= 1) {  // keys >= 196: pad/junk
            pa = 0.f;
            pb = 0.f;
          }
          sum0 += pa;
          sum1 += pb;
          p0e[e] = pa;
          p1e[e] = pb;
        }
        pw0[half * 2 + 0] = cvt_pk_bf16(p0e[0], p0e[1]);
        pw0[half * 2 + 1] = cvt_pk_bf16(p0e[2], p0e[3]);
        pw1[half * 2 + 0] = cvt_pk_bf16(p1e[0], p1e[1]);
        pw1[half * 2 + 1] = cvt_pk_bf16(p1e[2], p1e[3]);
      } else {  // tau == 6 high half: keys 208-223 virtual
        pw0[2] = 0u;
        pw0[3] = 0u;
        pw1[2] = 0u;
        pw1[3] = 0u;
      }
    }
    const short8v vf =
        __builtin_shufflevector(vlo[tau], vhi[tau], 0, 1, 2, 3, 4, 5, 6, 7);
    const uint4 u0 = make_uint4(pw0[0], pw0[1], pw0[2], pw0[3]);
    const uint4 u1 = make_uint4(pw1[0], pw1[1], pw1[2], pw1[3]);
    oacc0 = mfma_bf16(vf, __builtin_bit_cast(short8v, u0), oacc0);
    oacc1 = mfma_bf16(vf, __builtin_bit_cast(short8v, u1), oacc1);
  }

  // ---- softmax denominators (row spread across lane groups ^16, ^32) ----
  sum0 += __shfl_xor(sum0, 16);
  sum0 += __shfl_xor(sum0, 32);
  sum1 += __shfl_xor(sum1, 16);
  sum1 += __shfl_xor(sum1, 32);
  const float inv0 = 1.f / sum0;
  const float inv1 = 1.f / sum1;

  // ---- epilogue: lane holds O^T[c=4*hq+e][qrow]; scale by 1/sum ----
  {
    const int y = bh * BLK + (qrow0 >> 3);
    const int xx = bw * BLK + (qrow0 & 7);
    float* op = out + ((size_t)b * C + head * D + 4 * hq) * HW + y * W + xx;
#pragma unroll
    for (int e = 0; e < 4; ++e) op[(size_t)e * HW] = oacc0[e] * inv0;
  }
  {
    const int qrow1 = qrow0 + 16;
    const int y = bh * BLK + (qrow1 >> 3);
    const int xx = bw * BLK + (qrow1 & 7);
    float* op = out + ((size_t)b * C + head * D + 4 * hq) * HW + y * W + xx;
#pragma unroll
    for (int e = 0; e < 4; ++e) op[(size_t)e * HW] = oacc1[e] * inv1;
  }
  __builtin_amdgcn_s_setprio(0);
}

extern "C" void kernel_launch(void* const* d_in, const int* in_sizes, int n_in,
                              void* d_out, int out_size, void* d_ws,
                              size_t ws_size, hipStream_t stream) {
  const float* x = (const float*)d_in[0];      // (4, 64, 192, 192)
  const float* w_qkv = (const float*)d_in[1];  // (192, 64)
  const float* rel_h = (const float*)d_in[2];  // (1, 14, 1, 8)
  const float* rel_w = (const float*)d_in[3];  // (1, 1, 14, 8)
  float* out = (float*)d_out;                  // (4, 64, 192, 192)

  unsigned short* qkv = (unsigned short*)d_ws;  // (B, H, W, O) bf16

  qkv_mfma<<<B * HW / 128, 256, 0, stream>>>(x, w_qkv, qkv);
  attn_kernel<<<B * NH * NW * 2, 256, 0, stream>>>(qkv, rel_h, rel_w, out);
}

// Round 15
// 61.522 us; speedup vs baseline: 1.0316x; 1.0210x over previous
//
#include <hip/hip_runtime.h>
#include <hip/hip_bf16.h>

// Problem constants
constexpr int B = 4, C = 64, H = 192, W = 192;
constexpr int HEADS = 4, D = 16;           // d = C/HEADS
constexpr int BLK = 8, HALO = 3, WIN = 14; // WIN = BLK + 2*HALO
constexpr int NH = H / BLK, NW = W / BLK;  // 24 x 24 windows
constexpr int HW = H * W;                  // 36864
constexpr int O = 3 * C;                   // 192 qkv channels

// attn LDS layout (units: shorts). One block = one window x 2 heads.
// K: [200 rows][stride 32] = 2 heads x 2 chunks x 8ch, 4-chunk XOR swizzle.
// K padded to 6656 so V plane 0 starts 1024-B aligned (13312 B).
// V: 2 planes of [208][16], stride 3344 shorts.
constexpr int K_ROWS = 200;
constexpr int KSTRIDE = 32;                 // shorts per K row (64 B)
constexpr int K_OFF = 0;
constexpr int V_OFF = 6656;                 // 13312 B, 1024-aligned
constexpr int VPLANE = 208 * 16 + 16;       // 3344 shorts per head plane
constexpr int RH_OFF = V_OFF + 2 * VPLANE;  // rel_h bf16 [16][8]
constexpr int RW_OFF = RH_OFF + 128;        // rel_w bf16 [16][8]
constexpr int LDS_TOT = RW_OFF + 128;       // 13600 shorts = 27200 B

constexpr int K_ITEMS = K_ROWS * 4;         // 800 (pixel x {2 heads x 2 chunks})
constexpr int TOT_ITEMS = K_ITEMS + 208 * 4;  // 1632

typedef __attribute__((ext_vector_type(4))) short short4v;
typedef __attribute__((ext_vector_type(8))) short short8v;
typedef __attribute__((ext_vector_type(8))) __bf16 bf16x8;
typedef __attribute__((ext_vector_type(4))) float f32x4;

__device__ inline f32x4 mfma_bf16(short8v a, short8v b, f32x4 c) {
  return __builtin_amdgcn_mfma_f32_16x16x32_bf16(
      __builtin_bit_cast(bf16x8, a), __builtin_bit_cast(bf16x8, b), c, 0, 0, 0);
}

__device__ inline unsigned short f2bf(float f) {
  __bf16 h = (__bf16)f;
  return __builtin_bit_cast(unsigned short, h);
}

// packed bf16 pair: lo = bf16(a), hi = bf16(b) — single HW instr (T12)
__device__ inline unsigned cvt_pk_bf16(float a, float b) {
  unsigned r;
  asm("v_cvt_pk_bf16_f32 %0, %1, %2" : "=v"(r) : "v"(a), "v"(b));
  return r;
}

// ---------------------------------------------------------------------------
// Kernel 1: qkv projection as MFMA GEMM (unchanged; near HBM floor).
// q rows pre-scaled by d^-0.5 * log2(e) so attention works in exp2 domain.
// ---------------------------------------------------------------------------
__global__ __launch_bounds__(256) void qkv_mfma(
    const float* __restrict__ x, const float* __restrict__ w,
    unsigned short* __restrict__ qkv) {
  __shared__ unsigned short wlds[192 * 64];
  const int tid = threadIdx.x;

  const float4* wf4 = reinterpret_cast<const float4*>(w);
#pragma unroll
  for (int it = 0; it < 12; ++it) {
    const int idx = it * 256 + tid;  // 3072 float4s
    const int o = idx >> 4;
    const int c = (idx & 15) << 2;
    const float4 wv = wf4[idx];
    ushort4 st;
    st.x = f2bf(wv.x);
    st.y = f2bf(wv.y);
    st.z = f2bf(wv.z);
    st.w = f2bf(wv.w);
    const int sw = (((c >> 3) ^ (o & 7)) << 3) + (c & 4);
    *reinterpret_cast<ushort4*>(&wlds[o * 64 + sw]) = st;
  }

  const int wave = tid >> 6, lane = tid & 63;
  const int p = lane & 15, g = lane >> 4;
  const int pix_w = blockIdx.x * 128 + wave * 32;
  const int b = pix_w / HW;
  const int hw = pix_w - b * HW + p;
  const float* xb = x + (size_t)b * C * HW;

  short8v xf[2][2];
#pragma unroll
  for (int pt = 0; pt < 2; ++pt) {
#pragma unroll
    for (int ks = 0; ks < 2; ++ks) {
      unsigned short u[8];
#pragma unroll
      for (int j = 0; j < 8; ++j)
        u[j] = f2bf(xb[(size_t)(ks * 32 + g * 8 + j) * HW + hw + pt * 16]);
      unsigned int pw[4];
#pragma unroll
      for (int e = 0; e < 4; ++e)
        pw[e] = (unsigned int)u[2 * e] | ((unsigned int)u[2 * e + 1] << 16);
      xf[pt][ks] = __builtin_bit_cast(short8v, *reinterpret_cast<uint4*>(pw));
    }
  }
  __syncthreads();

#pragma unroll
  for (int ot = 0; ot < 12; ++ot) {
    short8v af[2];
#pragma unroll
    for (int ks = 0; ks < 2; ++ks)
      af[ks] = *reinterpret_cast<const short8v*>(
          wlds + (ot * 16 + p) * 64 + (((((ks << 2) | g)) ^ (p & 7)) << 3));
    // q pre-scale: d^-0.5 * log2(e) -> attention uses exp2 directly
    const float s = (ot < 4) ? 0.25f * 1.44269504f : 1.0f;
#pragma unroll
    for (int pt = 0; pt < 2; ++pt) {
      f32x4 acc = {0.f, 0.f, 0.f, 0.f};
      acc = mfma_bf16(af[0], xf[pt][0], acc);
      acc = mfma_bf16(af[1], xf[pt][1], acc);
      ushort4 st;
      st.x = f2bf(acc[0] * s);
      st.y = f2bf(acc[1] * s);
      st.z = f2bf(acc[2] * s);
      st.w = f2bf(acc[3] * s);
      *reinterpret_cast<ushort4*>(
          qkv + (size_t)(pix_w + pt * 16 + p) * O + ot * 16 + g * 4) = st;
    }
  }
}

// ---------------------------------------------------------------------------
// Kernel 2: MFMA window attention v12 = R14 verbatim except the grid mapping:
// both (window, hpair) blocks now land on the SAME XCD (8 dispatch slots
// apart), restoring L2 sharing of the K/V cache lines (a pixel's K section is
// exactly one 128B line covering all 4 heads; R14's mapping split the pair
// across XCDs and doubled FETCH).
// ---------------------------------------------------------------------------
__global__ __launch_bounds__(256, 4) void attn_kernel(
    const unsigned short* __restrict__ qkv,
    const float* __restrict__ rel_h, const float* __restrict__ rel_w,
    float* __restrict__ out) {
  __shared__ __align__(16) unsigned short lds[LDS_TOT];

  const int tid = threadIdx.x;
  const int blk = blockIdx.x;
  // XCD-paired mapping: xcd = blk%8 (HW round-robin), j = blk/8;
  // hpair = j&1, window = xcd*288 + j/2. Both hpair blocks of a window:
  // blk = 16m+x and 16m+8+x -> same XCD, adjacent in that XCD's stream.
  const int xcd = blk & 7;
  const int j = blk >> 3;
  const int hpair = j & 1;              // heads {0,1} or {2,3}
  const int win = xcd * 288 + (j >> 1);
  const int b = win / (NH * NW);
  const int wrem = win - b * (NH * NW);
  const int bh = wrem / NW;
  const int bw = wrem - bh * NW;
  const int y0 = bh * BLK - HALO;
  const int x0 = bw * BLK - HALO;

  // ---- rel tables -> bf16 LDS (rows >= 14 clamped to 13) ----
  {
    const int i = tid & 127;
    const int rr = i >> 3, cc = i & 7;
    const int rc = (rr < WIN) ? rr : (WIN - 1);
    const float* src = (tid < 128) ? rel_h : rel_w;
    lds[((tid < 128) ? RH_OFF : RW_OFF) + i] = f2bf(src[rc * 8 + cc]);
  }

  // ---- staging phase 1: issue all K/V global loads (T14 split) ----
  // items 0..799 = K (200 pixels x 4 chunks), 800..1631 = V (208 x 4)
  uint4 raw[7];
#pragma unroll
  for (int it = 0; it < 7; ++it) {
    const int item = tid + it * 256;
    const bool isK = item < K_ITEMS;
    const int li = isK ? item : item - K_ITEMS;
    const int pixel = li >> 2;
    const int g = li & 3;  // (local head << 1) | chunk
    const int wy = pixel / WIN;
    const int wx = pixel - wy * WIN;
    const int y = y0 + wy, xx = x0 + wx;
    const bool inb = (item < TOT_ITEMS) & ((unsigned)y < (unsigned)H) &
                     ((unsigned)xx < (unsigned)W);
    uint4 rv = make_uint4(0u, 0u, 0u, 0u);
    if (inb)
      rv = *reinterpret_cast<const uint4*>(
          qkv + ((size_t)(b * HW + y * W + xx)) * O + (isK ? C : 2 * C) +
          (hpair << 5) + (g << 3));
    raw[it] = rv;
  }

  // ---- Q fragment prefetch (hq>=2 lanes supply q[0:8]/q[8:16] against the
  //      rel depth slots — no zero select anywhere) ----
  const int lane = tid & 63;
  const int wv = tid >> 6;              // 0..3
  const int lh = wv & 1;                // local head
  const int head = hpair * 2 + lh;      // global head
  const int qhalf = wv >> 1;
  const int r = lane & 15, hq = lane >> 4;
  const int qrow0 = qhalf * 32 + r;     // q2=0 row; q2=1 row = +16
  short8v qf0, qf1;
  {
    const int y = bh * BLK + (qrow0 >> 3);
    const int xx = bw * BLK + (qrow0 & 7);
    qf0 = *reinterpret_cast<const short8v*>(
        qkv + ((size_t)(b * HW + y * W + xx)) * O + head * D + (hq & 1) * 8);
    const int qrow1 = qrow0 + 16;
    const int y1 = bh * BLK + (qrow1 >> 3);
    const int xx1 = bw * BLK + (qrow1 & 7);
    qf1 = *reinterpret_cast<const short8v*>(
        qkv + ((size_t)(b * HW + y1 * W + xx1)) * O + head * D + (hq & 1) * 8);
  }

  // ---- staging phase 2: LDS writes ----
#pragma unroll
  for (int it = 0; it < 7; ++it) {
    const int item = tid + it * 256;
    if (item < TOT_ITEMS) {
      const bool isK = item < K_ITEMS;
      const int li = isK ? item : item - K_ITEMS;
      const int pixel = li >> 2;
      const int g = li & 3;
      if (isK) {
        const int ch = (g ^ pixel) & 3;  // 4-chunk XOR swizzle
        *reinterpret_cast<uint4*>(&lds[K_OFF + pixel * KSTRIDE + ch * 8]) =
            raw[it];
      } else {
        const int vlh = g >> 1, c8 = g & 1;
        *reinterpret_cast<uint4*>(
            &lds[V_OFF + vlh * VPLANE + pixel * 16 + c8 * 8]) = raw[it];
      }
    }
  }
  __syncthreads();

  // ---- per-lane A-frag LDS offsets (shorts), one per QK tile ----
  // hq<2: K row chunks (XOR'd); hq==2: rel_h[wy]; hq==3: rel_w[wx].
  // Tile 12 rows 200-207 read K-pad junk (finite LDS); those keys' p = 0.
  int koff[13];
#pragma unroll
  for (int t = 0; t < 13; ++t) {
    const int row = 16 * t + r;
    const int wy = row / WIN;
    const int wx = row - wy * WIN;
    const int a_k =
        K_OFF + row * KSTRIDE + (((((lh << 1) | (hq & 1)) ^ row) & 3) << 3);
    const int a_rh = RH_OFF + wy * 8;
    const int a_rw = RW_OFF + wx * 8;
    koff[t] = (hq < 2) ? a_k : ((hq == 2) ? a_rh : a_rw);
  }

  // ---- V^T fragments via hardware transpose-read (per-lane addr):
  //      lane l supplies base + 8*l; lane(r,hq) elem j = V[32*tau+4*hq+j][r];
  //      offset:512 gives +16 slots. ----
  const unsigned vbase_addr =
      (unsigned)(unsigned long long)(const void*)&lds[V_OFF + lh * VPLANE] +
      (unsigned)(lane * 8);
  short4v vlo[7], vhi[7];
#pragma unroll
  for (int tau = 0; tau < 7; ++tau) {
    const unsigned va = vbase_addr + tau * 1024;
    asm volatile("ds_read_b64_tr_b16 %0, %1" : "=v"(vlo[tau]) : "v"(va));
    if (tau < 6) {
      asm volatile("ds_read_b64_tr_b16 %0, %1 offset:512"
                   : "=v"(vhi[tau])
                   : "v"(va));
    } else {
      vhi[tau] = (short4v){0, 0, 0, 0};  // slots 208-223: pf is 0 anyway
    }
  }
  asm volatile("s_waitcnt lgkmcnt(0)" ::: "memory");
  __builtin_amdgcn_sched_barrier(0);

  __builtin_amdgcn_s_setprio(1);

  // ---- fused streaming pass: QK -> exp2 -> pack -> PV, both q2 at once ----
  f32x4 oacc0 = {0.f, 0.f, 0.f, 0.f}, oacc1 = {0.f, 0.f, 0.f, 0.f};
  float sum0 = 0.f, sum1 = 0.f;
#pragma unroll
  for (int tau = 0; tau < 7; ++tau) {
    unsigned pw0[4], pw1[4];
#pragma unroll
    for (int half = 0; half < 2; ++half) {
      const int t = 2 * tau + half;
      if (t < 13) {
        const short8v kf = *reinterpret_cast<const short8v*>(&lds[koff[t]]);
        const f32x4 z4 = {0.f, 0.f, 0.f, 0.f};
        const f32x4 s0 = mfma_bf16(kf, qf0, z4);
        const f32x4 s1 = mfma_bf16(kf, qf1, z4);
        float p0e[4], p1e[4];
#pragma unroll
        for (int e = 0; e < 4; ++e) {
          float pa = __builtin_amdgcn_exp2f(s0[e]);
          float pb = __builtin_amdgcn_exp2f(s1[e]);
          if (t == 12 && hq >= 1) {  // keys >= 196: pad/junk
            pa = 0.f;
            pb = 0.f;
          }
          sum0 += pa;
          sum1 += pb;
          p0e[e] = pa;
          p1e[e] = pb;
        }
        pw0[half * 2 + 0] = cvt_pk_bf16(p0e[0], p0e[1]);
        pw0[half * 2 + 1] = cvt_pk_bf16(p0e[2], p0e[3]);
        pw1[half * 2 + 0] = cvt_pk_bf16(p1e[0], p1e[1]);
        pw1[half * 2 + 1] = cvt_pk_bf16(p1e[2], p1e[3]);
      } else {  // tau == 6 high half: keys 208-223 virtual
        pw0[2] = 0u;
        pw0[3] = 0u;
        pw1[2] = 0u;
        pw1[3] = 0u;
      }
    }
    const short8v vf =
        __builtin_shufflevector(vlo[tau], vhi[tau], 0, 1, 2, 3, 4, 5, 6, 7);
    const uint4 u0 = make_uint4(pw0[0], pw0[1], pw0[2], pw0[3]);
    const uint4 u1 = make_uint4(pw1[0], pw1[1], pw1[2], pw1[3]);
    oacc0 = mfma_bf16(vf, __builtin_bit_cast(short8v, u0), oacc0);
    oacc1 = mfma_bf16(vf, __builtin_bit_cast(short8v, u1), oacc1);
  }

  // ---- softmax denominators (row spread across lane groups ^16, ^32) ----
  sum0 += __shfl_xor(sum0, 16);
  sum0 += __shfl_xor(sum0, 32);
  sum1 += __shfl_xor(sum1, 16);
  sum1 += __shfl_xor(sum1, 32);
  const float inv0 = 1.f / sum0;
  const float inv1 = 1.f / sum1;

  // ---- epilogue: lane holds O^T[c=4*hq+e][qrow]; scale by 1/sum ----
  {
    const int y = bh * BLK + (qrow0 >> 3);
    const int xx = bw * BLK + (qrow0 & 7);
    float* op = out + ((size_t)b * C + head * D + 4 * hq) * HW + y * W + xx;
#pragma unroll
    for (int e = 0; e < 4; ++e) op[(size_t)e * HW] = oacc0[e] * inv0;
  }
  {
    const int qrow1 = qrow0 + 16;
    const int y = bh * BLK + (qrow1 >> 3);
    const int xx = bw * BLK + (qrow1 & 7);
    float* op = out + ((size_t)b * C + head * D + 4 * hq) * HW + y * W + xx;
#pragma unroll
    for (int e = 0; e < 4; ++e) op[(size_t)e * HW] = oacc1[e] * inv1;
  }
  __builtin_amdgcn_s_setprio(0);
}

extern "C" void kernel_launch(void* const* d_in, const int* in_sizes, int n_in,
                              void* d_out, int out_size, void* d_ws,
                              size_t ws_size, hipStream_t stream) {
  const float* x = (const float*)d_in[0];      // (4, 64, 192, 192)
  const float* w_qkv = (const float*)d_in[1];  // (192, 64)
  const float* rel_h = (const float*)d_in[2];  // (1, 14, 1, 8)
  const float* rel_w = (const float*)d_in[3];  // (1, 1, 14, 8)
  float* out = (float*)d_out;                  // (4, 64, 192, 192)

  unsigned short* qkv = (unsigned short*)d_ws;  // (B, H, W, O) bf16

  qkv_mfma<<<B * HW / 128, 256, 0, stream>>>(x, w_qkv, qkv);
  attn_kernel<<<B * NH * NW * 2, 256, 0, stream>>>(qkv, rel_h, rel_w, out);
}

// Round 18
// 61.506 us; speedup vs baseline: 1.0319x; 1.0003x over previous
//
#include <hip/hip_runtime.h>
#include <hip/hip_bf16.h>

// Problem constants
constexpr int B = 4, C = 64, H = 192, W = 192;
constexpr int HEADS = 4, D = 16;           // d = C/HEADS
constexpr int BLK = 8, HALO = 3, WIN = 14; // WIN = BLK + 2*HALO
constexpr int NH = H / BLK, NW = W / BLK;  // 24 x 24 windows
constexpr int HW = H * W;                  // 36864
constexpr int O = 3 * C;                   // 192 qkv channels

// attn LDS layout (units: shorts). One block = one window x 2 heads.
// K: [200 rows][stride 32] = 2 heads x 2 chunks x 8ch, 4-chunk XOR swizzle.
// K padded to 6656 so V plane 0 starts 1024-B aligned (13312 B).
// V: 2 planes of [208][16], stride 3344 shorts.
constexpr int K_ROWS = 200;
constexpr int KSTRIDE = 32;                 // shorts per K row (64 B)
constexpr int K_OFF = 0;
constexpr int V_OFF = 6656;                 // 13312 B, 1024-aligned
constexpr int VPLANE = 208 * 16 + 16;       // 3344 shorts per head plane
constexpr int RH_OFF = V_OFF + 2 * VPLANE;  // rel_h bf16 [16][8]
constexpr int RW_OFF = RH_OFF + 128;        // rel_w bf16 [16][8]
constexpr int LDS_TOT = RW_OFF + 128;       // 13600 shorts = 27200 B

constexpr int K_ITEMS = K_ROWS * 4;         // 800 (pixel x {2 heads x 2 chunks})
constexpr int TOT_ITEMS = K_ITEMS + 208 * 4;  // 1632

typedef __attribute__((ext_vector_type(4))) short short4v;
typedef __attribute__((ext_vector_type(8))) short short8v;
typedef __attribute__((ext_vector_type(8))) __bf16 bf16x8;
typedef __attribute__((ext_vector_type(4))) float f32x4;

__device__ inline f32x4 mfma_bf16(short8v a, short8v b, f32x4 c) {
  return __builtin_amdgcn_mfma_f32_16x16x32_bf16(
      __builtin_bit_cast(bf16x8, a), __builtin_bit_cast(bf16x8, b), c, 0, 0, 0);
}

__device__ inline unsigned short f2bf(float f) {
  __bf16 h = (__bf16)f;
  return __builtin_bit_cast(unsigned short, h);
}

// packed bf16 pair: lo = bf16(a), hi = bf16(b) — single HW instr (T12)
__device__ inline unsigned cvt_pk_bf16(float a, float b) {
  unsigned r;
  asm("v_cvt_pk_bf16_f32 %0, %1, %2" : "=v"(r) : "v"(a), "v"(b));
  return r;
}

// ---------------------------------------------------------------------------
// Kernel 1: qkv projection as MFMA GEMM (at HBM floor: 94 MB moved / 6.3 TB/s
// ~= 15 us). q rows pre-scaled by d^-0.5 * log2(e) for exp2-domain softmax.
// ---------------------------------------------------------------------------
__global__ __launch_bounds__(256) void qkv_mfma(
    const float* __restrict__ x, const float* __restrict__ w,
    unsigned short* __restrict__ qkv) {
  __shared__ unsigned short wlds[192 * 64];
  const int tid = threadIdx.x;

  const float4* wf4 = reinterpret_cast<const float4*>(w);
#pragma unroll
  for (int it = 0; it < 12; ++it) {
    const int idx = it * 256 + tid;  // 3072 float4s
    const int o = idx >> 4;
    const int c = (idx & 15) << 2;
    const float4 wv = wf4[idx];
    ushort4 st;
    st.x = f2bf(wv.x);
    st.y = f2bf(wv.y);
    st.z = f2bf(wv.z);
    st.w = f2bf(wv.w);
    const int sw = (((c >> 3) ^ (o & 7)) << 3) + (c & 4);
    *reinterpret_cast<ushort4*>(&wlds[o * 64 + sw]) = st;
  }

  const int wave = tid >> 6, lane = tid & 63;
  const int p = lane & 15, g = lane >> 4;
  const int pix_w = blockIdx.x * 128 + wave * 32;
  const int b = pix_w / HW;
  const int hw = pix_w - b * HW + p;
  const float* xb = x + (size_t)b * C * HW;

  short8v xf[2][2];
#pragma unroll
  for (int pt = 0; pt < 2; ++pt) {
#pragma unroll
    for (int ks = 0; ks < 2; ++ks) {
      unsigned short u[8];
#pragma unroll
      for (int j = 0; j < 8; ++j)
        u[j] = f2bf(xb[(size_t)(ks * 32 + g * 8 + j) * HW + hw + pt * 16]);
      unsigned int pw[4];
#pragma unroll
      for (int e = 0; e < 4; ++e)
        pw[e] = (unsigned int)u[2 * e] | ((unsigned int)u[2 * e + 1] << 16);
      xf[pt][ks] = __builtin_bit_cast(short8v, *reinterpret_cast<uint4*>(pw));
    }
  }
  __syncthreads();

#pragma unroll
  for (int ot = 0; ot < 12; ++ot) {
    short8v af[2];
#pragma unroll
    for (int ks = 0; ks < 2; ++ks)
      af[ks] = *reinterpret_cast<const short8v*>(
          wlds + (ot * 16 + p) * 64 + (((((ks << 2) | g)) ^ (p & 7)) << 3));
    // q pre-scale: d^-0.5 * log2(e) -> attention uses exp2 directly
    const float s = (ot < 4) ? 0.25f * 1.44269504f : 1.0f;
#pragma unroll
    for (int pt = 0; pt < 2; ++pt) {
      f32x4 acc = {0.f, 0.f, 0.f, 0.f};
      acc = mfma_bf16(af[0], xf[pt][0], acc);
      acc = mfma_bf16(af[1], xf[pt][1], acc);
      ushort4 st;
      st.x = f2bf(acc[0] * s);
      st.y = f2bf(acc[1] * s);
      st.z = f2bf(acc[2] * s);
      st.w = f2bf(acc[3] * s);
      *reinterpret_cast<ushort4*>(
          qkv + (size_t)(pix_w + pt * 16 + p) * O + ot * 16 + g * 4) = st;
    }
  }
}

// ---------------------------------------------------------------------------
// Kernel 2: MFMA window attention (R15-proven final form).
// - One block = (window, head-pair): 256 thr = 4 waves; XCD-paired grid
//   mapping keeps both hpair blocks of a window on the same XCD (L2 shares
//   the K/V lines: a pixel's K section is one 128B line for all 4 heads).
// - rel folded into MFMA spare depth (A 16-23 = rel_h, 24-31 = rel_w; B
//   carries q[0:8]/q[8:16] on hq>=2 lanes): sim = q*(k+rel) in matrix pipe.
// - V^T via ds_read_b64_tr_b16 (per-lane addr = base + 8*lane).
// - fused stream: QK -> exp2 -> cvt_pk bf16 -> PV for both q-subtiles; no
//   softmax max-pass (exp2-domain sims are O(1), fp32-safe).
// ---------------------------------------------------------------------------
__global__ __launch_bounds__(256, 4) void attn_kernel(
    const unsigned short* __restrict__ qkv,
    const float* __restrict__ rel_h, const float* __restrict__ rel_w,
    float* __restrict__ out) {
  __shared__ __align__(16) unsigned short lds[LDS_TOT];

  const int tid = threadIdx.x;
  const int blk = blockIdx.x;
  // XCD-paired mapping: xcd = blk%8 (HW round-robin), j = blk/8;
  // hpair = j&1, window = xcd*288 + j/2. Both hpair blocks of a window:
  // blk = 16m+x and 16m+8+x -> same XCD, adjacent in that XCD's stream.
  const int xcd = blk & 7;
  const int j = blk >> 3;
  const int hpair = j & 1;              // heads {0,1} or {2,3}
  const int win = xcd * 288 + (j >> 1);
  const int b = win / (NH * NW);
  const int wrem = win - b * (NH * NW);
  const int bh = wrem / NW;
  const int bw = wrem - bh * NW;
  const int y0 = bh * BLK - HALO;
  const int x0 = bw * BLK - HALO;

  // ---- rel tables -> bf16 LDS (rows >= 14 clamped to 13) ----
  {
    const int i = tid & 127;
    const int rr = i >> 3, cc = i & 7;
    const int rc = (rr < WIN) ? rr : (WIN - 1);
    const float* src = (tid < 128) ? rel_h : rel_w;
    lds[((tid < 128) ? RH_OFF : RW_OFF) + i] = f2bf(src[rc * 8 + cc]);
  }

  // ---- staging phase 1: issue all K/V global loads (T14 split) ----
  // items 0..799 = K (200 pixels x 4 chunks), 800..1631 = V (208 x 4)
  uint4 raw[7];
#pragma unroll
  for (int it = 0; it < 7; ++it) {
    const int item = tid + it * 256;
    const bool isK = item < K_ITEMS;
    const int li = isK ? item : item - K_ITEMS;
    const int pixel = li >> 2;
    const int g = li & 3;  // (local head << 1) | chunk
    const int wy = pixel / WIN;
    const int wx = pixel - wy * WIN;
    const int y = y0 + wy, xx = x0 + wx;
    const bool inb = (item < TOT_ITEMS) & ((unsigned)y < (unsigned)H) &
                     ((unsigned)xx < (unsigned)W);
    uint4 rv = make_uint4(0u, 0u, 0u, 0u);
    if (inb)
      rv = *reinterpret_cast<const uint4*>(
          qkv + ((size_t)(b * HW + y * W + xx)) * O + (isK ? C : 2 * C) +
          (hpair << 5) + (g << 3));
    raw[it] = rv;
  }

  // ---- Q fragment prefetch (hq>=2 lanes supply q[0:8]/q[8:16] against the
  //      rel depth slots — no zero select anywhere) ----
  const int lane = tid & 63;
  const int wv = tid >> 6;              // 0..3
  const int lh = wv & 1;                // local head
  const int head = hpair * 2 + lh;      // global head
  const int qhalf = wv >> 1;
  const int r = lane & 15, hq = lane >> 4;
  const int qrow0 = qhalf * 32 + r;     // q2=0 row; q2=1 row = +16
  short8v qf0, qf1;
  {
    const int y = bh * BLK + (qrow0 >> 3);
    const int xx = bw * BLK + (qrow0 & 7);
    qf0 = *reinterpret_cast<const short8v*>(
        qkv + ((size_t)(b * HW + y * W + xx)) * O + head * D + (hq & 1) * 8);
    const int qrow1 = qrow0 + 16;
    const int y1 = bh * BLK + (qrow1 >> 3);
    const int xx1 = bw * BLK + (qrow1 & 7);
    qf1 = *reinterpret_cast<const short8v*>(
        qkv + ((size_t)(b * HW + y1 * W + xx1)) * O + head * D + (hq & 1) * 8);
  }

  // ---- staging phase 2: LDS writes ----
#pragma unroll
  for (int it = 0; it < 7; ++it) {
    const int item = tid + it * 256;
    if (item < TOT_ITEMS) {
      const bool isK = item < K_ITEMS;
      const int li = isK ? item : item - K_ITEMS;
      const int pixel = li >> 2;
      const int g = li & 3;
      if (isK) {
        const int ch = (g ^ pixel) & 3;  // 4-chunk XOR swizzle
        *reinterpret_cast<uint4*>(&lds[K_OFF + pixel * KSTRIDE + ch * 8]) =
            raw[it];
      } else {
        const int vlh = g >> 1, c8 = g & 1;
        *reinterpret_cast<uint4*>(
            &lds[V_OFF + vlh * VPLANE + pixel * 16 + c8 * 8]) = raw[it];
      }
    }
  }
  __syncthreads();

  // ---- per-lane A-frag LDS offsets (shorts), one per QK tile ----
  // hq<2: K row chunks (XOR'd); hq==2: rel_h[wy]; hq==3: rel_w[wx].
  // Tile 12 rows 200-207 read K-pad junk (finite LDS); those keys' p = 0.
  int koff[13];
#pragma unroll
  for (int t = 0; t < 13; ++t) {
    const int row = 16 * t + r;
    const int wy = row / WIN;
    const int wx = row - wy * WIN;
    const int a_k =
        K_OFF + row * KSTRIDE + (((((lh << 1) | (hq & 1)) ^ row) & 3) << 3);
    const int a_rh = RH_OFF + wy * 8;
    const int a_rw = RW_OFF + wx * 8;
    koff[t] = (hq < 2) ? a_k : ((hq == 2) ? a_rh : a_rw);
  }

  // ---- V^T fragments via hardware transpose-read (per-lane addr):
  //      lane l supplies base + 8*l; lane(r,hq) elem j = V[32*tau+4*hq+j][r];
  //      offset:512 gives +16 slots. ----
  const unsigned vbase_addr =
      (unsigned)(unsigned long long)(const void*)&lds[V_OFF + lh * VPLANE] +
      (unsigned)(lane * 8);
  short4v vlo[7], vhi[7];
#pragma unroll
  for (int tau = 0; tau < 7; ++tau) {
    const unsigned va = vbase_addr + tau * 1024;
    asm volatile("ds_read_b64_tr_b16 %0, %1" : "=v"(vlo[tau]) : "v"(va));
    if (tau < 6) {
      asm volatile("ds_read_b64_tr_b16 %0, %1 offset:512"
                   : "=v"(vhi[tau])
                   : "v"(va));
    } else {
      vhi[tau] = (short4v){0, 0, 0, 0};  // slots 208-223: pf is 0 anyway
    }
  }
  asm volatile("s_waitcnt lgkmcnt(0)" ::: "memory");
  __builtin_amdgcn_sched_barrier(0);

  __builtin_amdgcn_s_setprio(1);

  // ---- fused streaming pass: QK -> exp2 -> pack -> PV, both q2 at once ----
  f32x4 oacc0 = {0.f, 0.f, 0.f, 0.f}, oacc1 = {0.f, 0.f, 0.f, 0.f};
  float sum0 = 0.f, sum1 = 0.f;
#pragma unroll
  for (int tau = 0; tau < 7; ++tau) {
    unsigned pw0[4], pw1[4];
#pragma unroll
    for (int half = 0; half < 2; ++half) {
      const int t = 2 * tau + half;
      if (t < 13) {
        const short8v kf = *reinterpret_cast<const short8v*>(&lds[koff[t]]);
        const f32x4 z4 = {0.f, 0.f, 0.f, 0.f};
        const f32x4 s0 = mfma_bf16(kf, qf0, z4);
        const f32x4 s1 = mfma_bf16(kf, qf1, z4);
        float p0e[4], p1e[4];
#pragma unroll
        for (int e = 0; e < 4; ++e) {
          float pa = __builtin_amdgcn_exp2f(s0[e]);
          float pb = __builtin_amdgcn_exp2f(s1[e]);
          if (t == 12 && hq >= 1) {  // keys >= 196: pad/junk
            pa = 0.f;
            pb = 0.f;
          }
          sum0 += pa;
          sum1 += pb;
          p0e[e] = pa;
          p1e[e] = pb;
        }
        pw0[half * 2 + 0] = cvt_pk_bf16(p0e[0], p0e[1]);
        pw0[half * 2 + 1] = cvt_pk_bf16(p0e[2], p0e[3]);
        pw1[half * 2 + 0] = cvt_pk_bf16(p1e[0], p1e[1]);
        pw1[half * 2 + 1] = cvt_pk_bf16(p1e[2], p1e[3]);
      } else {  // tau == 6 high half: keys 208-223 virtual
        pw0[2] = 0u;
        pw0[3] = 0u;
        pw1[2] = 0u;
        pw1[3] = 0u;
      }
    }
    const short8v vf =
        __builtin_shufflevector(vlo[tau], vhi[tau], 0, 1, 2, 3, 4, 5, 6, 7);
    const uint4 u0 = make_uint4(pw0[0], pw0[1], pw0[2], pw0[3]);
    const uint4 u1 = make_uint4(pw1[0], pw1[1], pw1[2], pw1[3]);
    oacc0 = mfma_bf16(vf, __builtin_bit_cast(short8v, u0), oacc0);
    oacc1 = mfma_bf16(vf, __builtin_bit_cast(short8v, u1), oacc1);
  }

  // ---- softmax denominators (row spread across lane groups ^16, ^32) ----
  sum0 += __shfl_xor(sum0, 16);
  sum0 += __shfl_xor(sum0, 32);
  sum1 += __shfl_xor(sum1, 16);
  sum1 += __shfl_xor(sum1, 32);
  const float inv0 = 1.f / sum0;
  const float inv1 = 1.f / sum1;

  // ---- epilogue: lane holds O^T[c=4*hq+e][qrow]; scale by 1/sum ----
  {
    const int y = bh * BLK + (qrow0 >> 3);
    const int xx = bw * BLK + (qrow0 & 7);
    float* op = out + ((size_t)b * C + head * D + 4 * hq) * HW + y * W + xx;
#pragma unroll
    for (int e = 0; e < 4; ++e) op[(size_t)e * HW] = oacc0[e] * inv0;
  }
  {
    const int qrow1 = qrow0 + 16;
    const int y = bh * BLK + (qrow1 >> 3);
    const int xx = bw * BLK + (qrow1 & 7);
    float* op = out + ((size_t)b * C + head * D + 4 * hq) * HW + y * W + xx;
#pragma unroll
    for (int e = 0; e < 4; ++e) op[(size_t)e * HW] = oacc1[e] * inv1;
  }
  __builtin_amdgcn_s_setprio(0);
}

extern "C" void kernel_launch(void* const* d_in, const int* in_sizes, int n_in,
                              void* d_out, int out_size, void* d_ws,
                              size_t ws_size, hipStream_t stream) {
  const float* x = (const float*)d_in[0];      // (4, 64, 192, 192)
  const float* w_qkv = (const float*)d_in[1];  // (192, 64)
  const float* rel_h = (const float*)d_in[2];  // (1, 14, 1, 8)
  const float* rel_w = (const float*)d_in[3];  // (1, 1, 14, 8)
  float* out = (float*)d_out;                  // (4, 64, 192, 192)

  unsigned short* qkv = (unsigned short*)d_ws;  // (B, H, W, O) bf16

  qkv_mfma<<<B * HW / 128, 256, 0, stream>>>(x, w_qkv, qkv);
  attn_kernel<<<B * NH * NW * 2, 256, 0, stream>>>(qkv, rel_h, rel_w, out);
}